// Round 1
// baseline (2037.055 us; speedup 1.0000x reference)
//
#include <hip/hip_runtime.h>
#include <math.h>

#define CH    64
#define WW    192
#define HH    192
#define HWSZ  (192*192)
#define KK    49
#define ROWP  68   // padded LDS row: 68%32=4 banks stride -> 2-way (free)

// ---------------------------------------------------------------------------
// k_prep: build (a) circular-conv kernels kr from fft_w, (b) k-major deform
// weights wT[k][o][c], (c) tap-major 3x3 weights w2T[tap][o][c].
//
// irfft2(rfft2(x) * W) with real W[8,5] == circular conv with
// kr[u,v] = (1/64) * sum_{ky,kx in 8x8} Wext[ky,kx] * cos(2pi(ky*u+kx*v)/8),
// Wext[ky,kx] = W[ky,kx] (kx<=4) else W[(-ky)%8, 8-kx].
// ---------------------------------------------------------------------------
__device__ const float c_cos8[8] = {
    1.f, 0.70710678118654752f, 0.f, -0.70710678118654752f,
   -1.f, -0.70710678118654752f, 0.f, 0.70710678118654752f };

__global__ void k_prep(const float* __restrict__ fw,   // [64,1,1,8,5]
                       const float* __restrict__ wd,   // [64,64,7,7]
                       const float* __restrict__ w2,   // [64,64,3,3]
                       float* __restrict__ krT,        // [64 uv][64 c]
                       float* __restrict__ wT,         // [49][64 o][64 c]
                       float* __restrict__ w2T)        // [9][64 o][64 c]
{
    int tid = blockIdx.x * blockDim.x + threadIdx.x;
    int nt  = gridDim.x * blockDim.x;
    for (int t = tid; t < 64 * 64; t += nt) {
        int uv = t >> 6, c = t & 63;
        int u = uv >> 3, v = uv & 7;
        float acc = 0.f;
        for (int ky = 0; ky < 8; ky++)
            for (int kx = 0; kx < 8; kx++) {
                float wv = (kx <= 4) ? fw[c * 40 + ky * 5 + kx]
                                     : fw[c * 40 + ((8 - ky) & 7) * 5 + (8 - kx)];
                acc += wv * c_cos8[(ky * u + kx * v) & 7];
            }
        krT[uv * 64 + c] = acc * (1.f / 64.f);
    }
    for (int t = tid; t < KK * 4096; t += nt) {
        int k = t / 4096, rem = t & 4095;
        int o = rem >> 6, c = rem & 63;
        wT[t] = wd[(o * 64 + c) * KK + k];
    }
    for (int t = tid; t < 9 * 4096; t += nt) {
        int tap = t / 4096, rem = t & 4095;
        int o = rem >> 6, c = rem & 63;
        w2T[t] = w2[(o * 64 + c) * 9 + tap];
    }
}

// ---------------------------------------------------------------------------
// k_deform: modulated deformable conv v2 (7x7, pad 3) fused with 1x1 w_conv1.
// Block = 16x4 pixel tile (64 px), 256 threads.
//   sampling role: lane c = t&63 samples 16 px of its channel per tap k
//   compute role : 4o x 4px microtile per thread (o-tile = (t>>4)*4, x = t&15)
// rev output layout: [px][64 o] (pixel-major, coalesced)
// ---------------------------------------------------------------------------
__global__ __launch_bounds__(256) void k_deform(
    const float* __restrict__ enc, const float* __restrict__ off,
    const float* __restrict__ msk, const float* __restrict__ wT,
    const float* __restrict__ wc1, float* __restrict__ rev)
{
    __shared__ __align__(16) float s[64 * ROWP];   // samples [px][c]
    __shared__ __align__(16) float wk[64 * ROWP];  // weights [o][c]; reused as d[px][o]

    int t = threadIdx.x;
    int bx = blockIdx.x % 12, by = blockIdx.x / 12;
    int gx0 = bx * 16, gy0 = by * 4;

    // sampling role
    int sc  = t & 63;
    int spg = t >> 6;           // tile row 0..3
    int sgy = gy0 + spg;
    const float* encC = enc + sc * HWSZ;

    // compute role
    int ot  = (t >> 4) * 4;
    int pxl = t & 15;

    float acc[4][4];
#pragma unroll
    for (int i = 0; i < 4; i++)
#pragma unroll
        for (int j = 0; j < 4; j++) acc[i][j] = 0.f;

    for (int k = 0; k < KK; k++) {
        // stage weights wT[k] -> wk[o][c]
#pragma unroll
        for (int r = 0; r < 16; r++) {
            int idx = t + r * 256;
            int o = idx >> 6, c = idx & 63;
            wk[o * ROWP + c] = wT[k * 4096 + idx];
        }
        // sample 16 pixels for channel sc
        int ky = k / 7, kx = k % 7;
#pragma unroll 4
        for (int i = 0; i < 16; i++) {
            int gx = gx0 + i;
            int gp = sgy * WW + gx;
            float dy = off[(2 * k) * HWSZ + gp];
            float dx = off[(2 * k + 1) * HWSZ + gp];
            float m  = msk[k * HWSZ + gp];
            float y = (float)(sgy - 3 + ky) + dy;
            float x = (float)(gx  - 3 + kx) + dx;
            float y0 = floorf(y), x0 = floorf(x);
            float wy = y - y0, wx = x - x0;
            float y1 = y0 + 1.f, x1 = x0 + 1.f;
            bool vy0 = (y0 >= 0.f) & (y0 < 192.f);
            bool vy1 = (y1 >= 0.f) & (y1 < 192.f);
            bool vx0 = (x0 >= 0.f) & (x0 < 192.f);
            bool vx1 = (x1 >= 0.f) & (x1 < 192.f);
            int iy0 = (int)y0, ix0 = (int)x0;
            float v00 = (vy0 & vx0) ? encC[iy0 * WW + ix0]       : 0.f;
            float v01 = (vy0 & vx1) ? encC[iy0 * WW + ix0 + 1]   : 0.f;
            float v10 = (vy1 & vx0) ? encC[(iy0+1) * WW + ix0]   : 0.f;
            float v11 = (vy1 & vx1) ? encC[(iy0+1) * WW + ix0+1] : 0.f;
            float v = (1.f - wy) * ((1.f - wx) * v00 + wx * v01)
                    +        wy  * ((1.f - wx) * v10 + wx * v11);
            s[(spg * 16 + i) * ROWP + sc] = v * m;
        }
        __syncthreads();
        // accumulate: acc[i][j] += sum_c wk[ot+i][c] * s[pxl+16j][c]
#pragma unroll
        for (int c4 = 0; c4 < 16; c4++) {
            float4 wv[4], sv[4];
#pragma unroll
            for (int i = 0; i < 4; i++)
                wv[i] = *(const float4*)&wk[(ot + i) * ROWP + c4 * 4];
#pragma unroll
            for (int j = 0; j < 4; j++)
                sv[j] = *(const float4*)&s[(pxl + 16 * j) * ROWP + c4 * 4];
#pragma unroll
            for (int i = 0; i < 4; i++)
#pragma unroll
                for (int j = 0; j < 4; j++)
                    acc[i][j] += wv[i].x * sv[j].x + wv[i].y * sv[j].y
                               + wv[i].z * sv[j].z + wv[i].w * sv[j].w;
        }
        __syncthreads();
    }

    // deform result d[px][o] into wk (reused)
#pragma unroll
    for (int j = 0; j < 4; j++) {
        float4 dv = make_float4(acc[0][j], acc[1][j], acc[2][j], acc[3][j]);
        *(float4*)&wk[(pxl + 16 * j) * ROWP + ot] = dv;
    }
    __syncthreads();

    // fused 1x1 conv: rev[px][o2] = sum_o wc1[o2][o] * d[px][o]
    float a2[4][4];
#pragma unroll
    for (int i = 0; i < 4; i++)
#pragma unroll
        for (int j = 0; j < 4; j++) a2[i][j] = 0.f;
#pragma unroll
    for (int c4 = 0; c4 < 16; c4++) {
        float4 wv[4], sv[4];
#pragma unroll
        for (int i = 0; i < 4; i++)
            wv[i] = *(const float4*)&wc1[(ot + i) * 64 + c4 * 4];
#pragma unroll
        for (int j = 0; j < 4; j++)
            sv[j] = *(const float4*)&wk[(pxl + 16 * j) * ROWP + c4 * 4];
#pragma unroll
        for (int i = 0; i < 4; i++)
#pragma unroll
            for (int j = 0; j < 4; j++)
                a2[i][j] += wv[i].x * sv[j].x + wv[i].y * sv[j].y
                          + wv[i].z * sv[j].z + wv[i].w * sv[j].w;
    }
#pragma unroll
    for (int j = 0; j < 4; j++) {
        int gp = (gy0 + j) * WW + gx0 + pxl;
        float4 rv = make_float4(a2[0][j], a2[1][j], a2[2][j], a2[3][j]);
        *(float4*)&rev[gp * 64 + ot] = rv;
    }
}

// ---------------------------------------------------------------------------
// k_fft: per 8x8 patch: e0 = w_proj_in @ enc (1x1 conv), then per-channel
// circular conv with kr.  Block = 1 patch, 256 threads.
// e1 output layout: [px][64 c]
// ---------------------------------------------------------------------------
__global__ __launch_bounds__(256) void k_fft(
    const float* __restrict__ enc, const float* __restrict__ wpi,
    const float* __restrict__ krT, float* __restrict__ e1)
{
    __shared__ __align__(16) float encP[64 * ROWP];  // [px][c]
    __shared__ __align__(16) float e0[64 * ROWP];    // [px][o]
    int t = threadIdx.x;
    int pbx = blockIdx.x % 24, pby = blockIdx.x / 24;
    int gx0 = pbx * 8, gy0 = pby * 8;

#pragma unroll
    for (int r = 0; r < 16; r++) {
        int idx = t + r * 256;
        int px = idx & 63, c = idx >> 6;
        int gy = gy0 + (px >> 3), gx = gx0 + (px & 7);
        encP[px * ROWP + c] = enc[c * HWSZ + gy * WW + gx];
    }
    __syncthreads();

    // proj_in matvec: e0[px][o] = sum_c wpi[o][c] * encP[px][c]
    int ot = (t >> 4) * 4, pxl = t & 15;
    float acc[4][4];
#pragma unroll
    for (int i = 0; i < 4; i++)
#pragma unroll
        for (int j = 0; j < 4; j++) acc[i][j] = 0.f;
#pragma unroll
    for (int c4 = 0; c4 < 16; c4++) {
        float4 wv[4], sv[4];
#pragma unroll
        for (int i = 0; i < 4; i++)
            wv[i] = *(const float4*)&wpi[(ot + i) * 64 + c4 * 4];
#pragma unroll
        for (int j = 0; j < 4; j++)
            sv[j] = *(const float4*)&encP[(pxl + 16 * j) * ROWP + c4 * 4];
#pragma unroll
        for (int i = 0; i < 4; i++)
#pragma unroll
            for (int j = 0; j < 4; j++)
                acc[i][j] += wv[i].x * sv[j].x + wv[i].y * sv[j].y
                           + wv[i].z * sv[j].z + wv[i].w * sv[j].w;
    }
#pragma unroll
    for (int j = 0; j < 4; j++) {
        float4 dv = make_float4(acc[0][j], acc[1][j], acc[2][j], acc[3][j]);
        *(float4*)&e0[(pxl + 16 * j) * ROWP + ot] = dv;
    }
    __syncthreads();

    // circular conv: out[y][x] = sum_{u,v} kr[u][v] * e0[(y-u)%8][(x-v)%8]
    int o = t & 63;
    int yb = t >> 6;
#pragma unroll
    for (int yy = 0; yy < 2; yy++) {
        int y = yb + yy * 4;
        float outr[8];
#pragma unroll
        for (int x = 0; x < 8; x++) outr[x] = 0.f;
#pragma unroll
        for (int u = 0; u < 8; u++) {
            int ry = (y - u + 8) & 7;
            float row[8];
#pragma unroll
            for (int rx = 0; rx < 8; rx++)
                row[rx] = e0[(ry * 8 + rx) * ROWP + o];
#pragma unroll
            for (int v = 0; v < 8; v++) {
                float kv = krT[(u * 8 + v) * 64 + o];
#pragma unroll
                for (int x = 0; x < 8; x++)
                    outr[x] += kv * row[(x - v + 8) & 7];
            }
        }
        int gy = gy0 + y;
#pragma unroll
        for (int x = 0; x < 8; x++)
            e1[(gy * WW + gx0 + x) * 64 + o] = outr[x];
    }
}

// ---------------------------------------------------------------------------
// k_conv3: e3 = conv3x3(e1 + rev, w_conv2, pad 1).  Block = 16x4 tile + halo.
// ---------------------------------------------------------------------------
__global__ __launch_bounds__(256) void k_conv3(
    const float* __restrict__ e1, const float* __restrict__ rev,
    const float* __restrict__ w2T, float* __restrict__ e3)
{
    __shared__ __align__(16) float tl[108 * ROWP];   // halo tile 18x6 [hp][c]
    int t = threadIdx.x;
    int bx = blockIdx.x % 12, by = blockIdx.x / 12;
    int gx0 = bx * 16, gy0 = by * 4;

#pragma unroll
    for (int r = 0; r < 27; r++) {
        int idx = t + r * 256;          // 6912 = 108*64
        int c = idx & 63, hp = idx >> 6;
        int hy = hp / 18, hx = hp % 18;
        int gy = gy0 + hy - 1, gx = gx0 + hx - 1;
        float v = 0.f;
        if (gy >= 0 && gy < HH && gx >= 0 && gx < WW) {
            int gp = gy * WW + gx;
            v = e1[gp * 64 + c] + rev[gp * 64 + c];
        }
        tl[hp * ROWP + c] = v;
    }
    __syncthreads();

    int ot = (t >> 4) * 4, pxl = t & 15;
    float acc[4][4];
#pragma unroll
    for (int i = 0; i < 4; i++)
#pragma unroll
        for (int j = 0; j < 4; j++) acc[i][j] = 0.f;

    for (int tap = 0; tap < 9; tap++) {
        int dy = tap / 3, dx = tap % 3;
        const float* wt = w2T + tap * 4096;
#pragma unroll
        for (int c4 = 0; c4 < 16; c4++) {
            float4 wv[4], sv[4];
#pragma unroll
            for (int i = 0; i < 4; i++)
                wv[i] = *(const float4*)&wt[(ot + i) * 64 + c4 * 4];
#pragma unroll
            for (int j = 0; j < 4; j++) {
                int hp = (j + dy) * 18 + (pxl + dx);
                sv[j] = *(const float4*)&tl[hp * ROWP + c4 * 4];
            }
#pragma unroll
            for (int i = 0; i < 4; i++)
#pragma unroll
                for (int j = 0; j < 4; j++)
                    acc[i][j] += wv[i].x * sv[j].x + wv[i].y * sv[j].y
                               + wv[i].z * sv[j].z + wv[i].w * sv[j].w;
        }
    }
#pragma unroll
    for (int j = 0; j < 4; j++) {
        int gp = (gy0 + j) * WW + gx0 + pxl;
        float4 rv = make_float4(acc[0][j], acc[1][j], acc[2][j], acc[3][j]);
        *(float4*)&e3[gp * 64 + ot] = rv;
    }
}

// ---------------------------------------------------------------------------
// k_out: feat = [e3 ; dec], g = w_proj_out @ feat (128->128),
// out[o] = g[o] * g[o+64].  Block = 16x4 tile.
// ---------------------------------------------------------------------------
#define ROWF 132  // 128 + 4 pad, multiple of 4

__global__ __launch_bounds__(256) void k_out(
    const float* __restrict__ e3, const float* __restrict__ dec,
    const float* __restrict__ wpo, float* __restrict__ out)
{
    __shared__ __align__(16) float f[64 * ROWF];
    int t = threadIdx.x;
    int bx = blockIdx.x % 12, by = blockIdx.x / 12;
    int gx0 = bx * 16, gy0 = by * 4;

#pragma unroll
    for (int r = 0; r < 16; r++) {          // e3 half: lanes c-consecutive
        int idx = t + r * 256;
        int c = idx & 63, px = idx >> 6;
        int gp = (gy0 + (px >> 4)) * WW + gx0 + (px & 15);
        f[px * ROWF + c] = e3[gp * 64 + c];
    }
#pragma unroll
    for (int r = 0; r < 16; r++) {          // dec half: lanes px-consecutive
        int idx = t + r * 256;
        int px = idx & 63, c = idx >> 6;
        int gp = (gy0 + (px >> 4)) * WW + gx0 + (px & 15);
        f[px * ROWF + 64 + c] = dec[c * HWSZ + gp];
    }
    __syncthreads();

    int ot = (t >> 4) * 4, pxl = t & 15;
    float a1[4][4], a2[4][4];
#pragma unroll
    for (int i = 0; i < 4; i++)
#pragma unroll
        for (int j = 0; j < 4; j++) { a1[i][j] = 0.f; a2[i][j] = 0.f; }

#pragma unroll
    for (int c4 = 0; c4 < 32; c4++) {
        float4 w1[4], w2[4], sv[4];
#pragma unroll
        for (int i = 0; i < 4; i++) {
            w1[i] = *(const float4*)&wpo[(ot + i) * 128 + c4 * 4];
            w2[i] = *(const float4*)&wpo[(ot + i + 64) * 128 + c4 * 4];
        }
#pragma unroll
        for (int j = 0; j < 4; j++)
            sv[j] = *(const float4*)&f[(pxl + 16 * j) * ROWF + c4 * 4];
#pragma unroll
        for (int i = 0; i < 4; i++)
#pragma unroll
            for (int j = 0; j < 4; j++) {
                a1[i][j] += w1[i].x * sv[j].x + w1[i].y * sv[j].y
                          + w1[i].z * sv[j].z + w1[i].w * sv[j].w;
                a2[i][j] += w2[i].x * sv[j].x + w2[i].y * sv[j].y
                          + w2[i].z * sv[j].z + w2[i].w * sv[j].w;
            }
    }
#pragma unroll
    for (int j = 0; j < 4; j++) {
        int gp = (gy0 + j) * WW + gx0 + pxl;
#pragma unroll
        for (int i = 0; i < 4; i++)
            out[(ot + i) * HWSZ + gp] = a1[i][j] * a2[i][j];
    }
}

// ---------------------------------------------------------------------------
extern "C" void kernel_launch(void* const* d_in, const int* in_sizes, int n_in,
                              void* d_out, int out_size, void* d_ws, size_t ws_size,
                              hipStream_t stream)
{
    const float* enc  = (const float*)d_in[0];
    const float* dec  = (const float*)d_in[1];
    const float* ioff = (const float*)d_in[2];
    const float* iwt  = (const float*)d_in[3];
    const float* wpi  = (const float*)d_in[4];
    const float* fw   = (const float*)d_in[5];
    const float* wpo  = (const float*)d_in[6];
    const float* wd   = (const float*)d_in[7];
    const float* wc1  = (const float*)d_in[8];
    const float* wc2  = (const float*)d_in[9];
    float* out = (float*)d_out;
    float* ws  = (float*)d_ws;

    float* krT = ws;                 //   4096
    float* wT  = ws + 4096;          // 200704
    float* w2T = ws + 204800;        //  36864
    float* rev = ws + 241664;        // 2359296  [px][64]
    float* e1  = ws + 2600960;       // 2359296  [px][64]
    float* e3  = ws + 4960256;       // 2359296  [px][64]
    // total: 7319552 floats = 29.3 MB

    hipLaunchKernelGGL(k_prep,   dim3(256), dim3(256), 0, stream, fw, wd, wc2, krT, wT, w2T);
    hipLaunchKernelGGL(k_deform, dim3(576), dim3(256), 0, stream, enc, ioff, iwt, wT, wc1, rev);
    hipLaunchKernelGGL(k_fft,    dim3(576), dim3(256), 0, stream, enc, wpi, krT, e1);
    hipLaunchKernelGGL(k_conv3,  dim3(576), dim3(256), 0, stream, e1, rev, w2T, e3);
    hipLaunchKernelGGL(k_out,    dim3(576), dim3(256), 0, stream, e3, dec, wpo, out);
}

// Round 2
// 1512.249 us; speedup vs baseline: 1.3470x; 1.3470x over previous
//
#include <hip/hip_runtime.h>
#include <math.h>

#define CH    64
#define WW    192
#define HH    192
#define HWSZ  (192*192)
#define KK    49
#define ROWP  68   // padded LDS row: 68%32=4 banks stride -> 2-way (free)

// ---------------------------------------------------------------------------
// k_prep: build (a) circular-conv kernels kr from fft_w, (b) k-major deform
// weights wT[k][o][c], (c) tap-major 3x3 weights w2T[tap][o][c].
//
// irfft2(rfft2(x) * W) with real W[8,5] == circular conv with
// kr[u,v] = (1/64) * sum_{ky,kx in 8x8} Wext[ky,kx] * cos(2pi(ky*u+kx*v)/8),
// Wext[ky,kx] = W[ky,kx] (kx<=4) else W[(-ky)%8, 8-kx].
// ---------------------------------------------------------------------------
__device__ const float c_cos8[8] = {
    1.f, 0.70710678118654752f, 0.f, -0.70710678118654752f,
   -1.f, -0.70710678118654752f, 0.f, 0.70710678118654752f };

__global__ void k_prep(const float* __restrict__ fw,   // [64,1,1,8,5]
                       const float* __restrict__ wd,   // [64,64,7,7]
                       const float* __restrict__ w2,   // [64,64,3,3]
                       float* __restrict__ krT,        // [64 uv][64 c]
                       float* __restrict__ wT,         // [49][64 o][64 c]
                       float* __restrict__ w2T)        // [9][64 o][64 c]
{
    int tid = blockIdx.x * blockDim.x + threadIdx.x;
    int nt  = gridDim.x * blockDim.x;
    for (int t = tid; t < 64 * 64; t += nt) {
        int uv = t >> 6, c = t & 63;
        int u = uv >> 3, v = uv & 7;
        float acc = 0.f;
        for (int ky = 0; ky < 8; ky++)
            for (int kx = 0; kx < 8; kx++) {
                float wv = (kx <= 4) ? fw[c * 40 + ky * 5 + kx]
                                     : fw[c * 40 + ((8 - ky) & 7) * 5 + (8 - kx)];
                acc += wv * c_cos8[(ky * u + kx * v) & 7];
            }
        krT[uv * 64 + c] = acc * (1.f / 64.f);
    }
    for (int t = tid; t < KK * 4096; t += nt) {
        int k = t / 4096, rem = t & 4095;
        int o = rem >> 6, c = rem & 63;
        wT[t] = wd[(o * 64 + c) * KK + k];
    }
    for (int t = tid; t < 9 * 4096; t += nt) {
        int tap = t / 4096, rem = t & 4095;
        int o = rem >> 6, c = rem & 63;
        w2T[t] = w2[(o * 64 + c) * 9 + tap];
    }
}

// ---------------------------------------------------------------------------
// k_trans: enc [c][p] -> encP [p][c]  (pixel-major for coalesced sampling)
// Block handles 64 consecutive pixels x 64 channels through LDS.
// ---------------------------------------------------------------------------
__global__ __launch_bounds__(256) void k_trans(
    const float* __restrict__ enc, float* __restrict__ encP)
{
    __shared__ float s[64 * 65];   // stride 65: conflict-free both phases
    int t = threadIdx.x;
    int base = blockIdx.x * 64;
#pragma unroll
    for (int r = 0; r < 16; r++) {
        int idx = t + r * 256;
        int p = idx & 63, c = idx >> 6;       // lanes: consecutive p, same c
        s[p * 65 + c] = enc[c * HWSZ + base + p];
    }
    __syncthreads();
#pragma unroll
    for (int r = 0; r < 16; r++) {
        int idx = t + r * 256;
        int c = idx & 63, p = idx >> 6;       // lanes: consecutive c, same p
        encP[(base + p) * 64 + c] = s[p * 65 + c];
    }
}

// ---------------------------------------------------------------------------
// k_deform: modulated deformable conv v2 (7x7, pad 3) fused with 1x1 w_conv1.
// Block = 16x4 pixel tile (64 px), 256 threads.
//   sampling role: quarter-wave = one sample point; 16 lanes x float4 = 64 ch
//                  -> every bilinear corner is one contiguous 256B load
//   compute role : 4o x 4px microtile per thread
// rev output layout: [px][64 o] (pixel-major, coalesced)
// ---------------------------------------------------------------------------
__global__ __launch_bounds__(256) void k_deform(
    const float* __restrict__ encP, const float* __restrict__ off,
    const float* __restrict__ msk, const float* __restrict__ wT,
    const float* __restrict__ wc1, float* __restrict__ rev)
{
    __shared__ __align__(16) float s[64 * ROWP];   // samples [px][c]
    __shared__ __align__(16) float wk[64 * ROWP];  // weights [o][c]; reused as d[px][o]

    int t = threadIdx.x;
    int bx = blockIdx.x % 12, by = blockIdx.x / 12;
    int gx0 = bx * 16, gy0 = by * 4;

    // sampling role: quarter-wave per sample point
    int lane = t & 63;
    int wv_i = t >> 6;            // wave 0..3
    int q    = lane >> 4;         // quarter 0..3
    int cc   = (lane & 15) * 4;   // channel group (float4)

    // compute role
    int ot  = (t >> 4) * 4;
    int pxl = t & 15;

    // weight staging role (float4): o row + channel group
    int so = t >> 4;              // 0..15
    int scc = (t & 15) * 4;

    float acc[4][4];
#pragma unroll
    for (int i = 0; i < 4; i++)
#pragma unroll
        for (int j = 0; j < 4; j++) acc[i][j] = 0.f;

    for (int k = 0; k < KK; k++) {
        // stage weights wT[k] -> wk[o][c], dwordx4 coalesced
#pragma unroll
        for (int r = 0; r < 4; r++) {
            int o = so + r * 16;
            *(float4*)&wk[o * ROWP + scc] =
                *(const float4*)&wT[k * 4096 + o * 64 + scc];
        }
        int ky = k / 7, kx = k % 7;
        const float* offY = off + (2 * k) * HWSZ;
        const float* offX = off + (2 * k + 1) * HWSZ;
        const float* mk   = msk + k * HWSZ;
#pragma unroll
        for (int i = 0; i < 4; i++) {
            int px  = wv_i * 16 + i * 4 + q;   // 0..63
            int py  = px >> 4, pxc = px & 15;
            int gy  = gy0 + py, gx = gx0 + pxc;
            int gp  = gy * WW + gx;
            float dy = offY[gp];               // quarter-wave broadcast
            float dx = offX[gp];
            float m  = mk[gp];
            float y = (float)(gy - 3 + ky) + dy;
            float x = (float)(gx - 3 + kx) + dx;
            float y0f = floorf(y), x0f = floorf(x);
            float wy = y - y0f, wx = x - x0f;
            int iy0 = (int)y0f, ix0 = (int)x0f;
            bool vy0 = (iy0 >= 0) & (iy0 < HH);
            bool vy1 = (iy0 + 1 >= 0) & (iy0 + 1 < HH);
            bool vx0 = (ix0 >= 0) & (ix0 < WW);
            bool vx1 = (ix0 + 1 >= 0) & (ix0 + 1 < WW);
            const float4 z4 = make_float4(0.f, 0.f, 0.f, 0.f);
            const float* b00 = encP + (iy0 * WW + ix0) * 64 + cc;
            float4 v00 = (vy0 & vx0) ? *(const float4*)(b00)            : z4;
            float4 v01 = (vy0 & vx1) ? *(const float4*)(b00 + 64)       : z4;
            float4 v10 = (vy1 & vx0) ? *(const float4*)(b00 + WW * 64)  : z4;
            float4 v11 = (vy1 & vx1) ? *(const float4*)(b00 + WW*64+64) : z4;
            float a00 = (1.f - wy) * (1.f - wx) * m;
            float a01 = (1.f - wy) * wx * m;
            float a10 = wy * (1.f - wx) * m;
            float a11 = wy * wx * m;
            float4 v;
            v.x = a00*v00.x + a01*v01.x + a10*v10.x + a11*v11.x;
            v.y = a00*v00.y + a01*v01.y + a10*v10.y + a11*v11.y;
            v.z = a00*v00.z + a01*v01.z + a10*v10.z + a11*v11.z;
            v.w = a00*v00.w + a01*v01.w + a10*v10.w + a11*v11.w;
            *(float4*)&s[px * ROWP + cc] = v;
        }
        __syncthreads();
        // accumulate: acc[i][j] += sum_c wk[ot+i][c] * s[pxl+16j][c]
#pragma unroll
        for (int c4 = 0; c4 < 16; c4++) {
            float4 wv[4], sv[4];
#pragma unroll
            for (int i = 0; i < 4; i++)
                wv[i] = *(const float4*)&wk[(ot + i) * ROWP + c4 * 4];
#pragma unroll
            for (int j = 0; j < 4; j++)
                sv[j] = *(const float4*)&s[(pxl + 16 * j) * ROWP + c4 * 4];
#pragma unroll
            for (int i = 0; i < 4; i++)
#pragma unroll
                for (int j = 0; j < 4; j++)
                    acc[i][j] += wv[i].x * sv[j].x + wv[i].y * sv[j].y
                               + wv[i].z * sv[j].z + wv[i].w * sv[j].w;
        }
        __syncthreads();
    }

    // deform result d[px][o] into wk (reused)
#pragma unroll
    for (int j = 0; j < 4; j++) {
        float4 dv = make_float4(acc[0][j], acc[1][j], acc[2][j], acc[3][j]);
        *(float4*)&wk[(pxl + 16 * j) * ROWP + ot] = dv;
    }
    __syncthreads();

    // fused 1x1 conv: rev[px][o2] = sum_o wc1[o2][o] * d[px][o]
    float a2[4][4];
#pragma unroll
    for (int i = 0; i < 4; i++)
#pragma unroll
        for (int j = 0; j < 4; j++) a2[i][j] = 0.f;
#pragma unroll
    for (int c4 = 0; c4 < 16; c4++) {
        float4 wv[4], sv[4];
#pragma unroll
        for (int i = 0; i < 4; i++)
            wv[i] = *(const float4*)&wc1[(ot + i) * 64 + c4 * 4];
#pragma unroll
        for (int j = 0; j < 4; j++)
            sv[j] = *(const float4*)&wk[(pxl + 16 * j) * ROWP + c4 * 4];
#pragma unroll
        for (int i = 0; i < 4; i++)
#pragma unroll
            for (int j = 0; j < 4; j++)
                a2[i][j] += wv[i].x * sv[j].x + wv[i].y * sv[j].y
                          + wv[i].z * sv[j].z + wv[i].w * sv[j].w;
    }
#pragma unroll
    for (int j = 0; j < 4; j++) {
        int gp = (gy0 + j) * WW + gx0 + pxl;
        float4 rv = make_float4(a2[0][j], a2[1][j], a2[2][j], a2[3][j]);
        *(float4*)&rev[gp * 64 + ot] = rv;
    }
}

// ---------------------------------------------------------------------------
// k_fft: per 8x8 patch: e0 = w_proj_in @ enc (1x1 conv), then per-channel
// circular conv with kr.  Block = 1 patch, 256 threads.
// e1 output layout: [px][64 c]
// ---------------------------------------------------------------------------
__global__ __launch_bounds__(256) void k_fft(
    const float* __restrict__ enc, const float* __restrict__ wpi,
    const float* __restrict__ krT, float* __restrict__ e1)
{
    __shared__ __align__(16) float encP[64 * ROWP];  // [px][c]
    __shared__ __align__(16) float e0[64 * ROWP];    // [px][o]
    int t = threadIdx.x;
    int pbx = blockIdx.x % 24, pby = blockIdx.x / 24;
    int gx0 = pbx * 8, gy0 = pby * 8;

#pragma unroll
    for (int r = 0; r < 16; r++) {
        int idx = t + r * 256;
        int px = idx & 63, c = idx >> 6;
        int gy = gy0 + (px >> 3), gx = gx0 + (px & 7);
        encP[px * ROWP + c] = enc[c * HWSZ + gy * WW + gx];
    }
    __syncthreads();

    // proj_in matvec: e0[px][o] = sum_c wpi[o][c] * encP[px][c]
    int ot = (t >> 4) * 4, pxl = t & 15;
    float acc[4][4];
#pragma unroll
    for (int i = 0; i < 4; i++)
#pragma unroll
        for (int j = 0; j < 4; j++) acc[i][j] = 0.f;
#pragma unroll
    for (int c4 = 0; c4 < 16; c4++) {
        float4 wv[4], sv[4];
#pragma unroll
        for (int i = 0; i < 4; i++)
            wv[i] = *(const float4*)&wpi[(ot + i) * 64 + c4 * 4];
#pragma unroll
        for (int j = 0; j < 4; j++)
            sv[j] = *(const float4*)&encP[(pxl + 16 * j) * ROWP + c4 * 4];
#pragma unroll
        for (int i = 0; i < 4; i++)
#pragma unroll
            for (int j = 0; j < 4; j++)
                acc[i][j] += wv[i].x * sv[j].x + wv[i].y * sv[j].y
                           + wv[i].z * sv[j].z + wv[i].w * sv[j].w;
    }
#pragma unroll
    for (int j = 0; j < 4; j++) {
        float4 dv = make_float4(acc[0][j], acc[1][j], acc[2][j], acc[3][j]);
        *(float4*)&e0[(pxl + 16 * j) * ROWP + ot] = dv;
    }
    __syncthreads();

    // circular conv: out[y][x] = sum_{u,v} kr[u][v] * e0[(y-u)%8][(x-v)%8]
    int o = t & 63;
    int yb = t >> 6;
#pragma unroll
    for (int yy = 0; yy < 2; yy++) {
        int y = yb + yy * 4;
        float outr[8];
#pragma unroll
        for (int x = 0; x < 8; x++) outr[x] = 0.f;
#pragma unroll
        for (int u = 0; u < 8; u++) {
            int ry = (y - u + 8) & 7;
            float row[8];
#pragma unroll
            for (int rx = 0; rx < 8; rx++)
                row[rx] = e0[(ry * 8 + rx) * ROWP + o];
#pragma unroll
            for (int v = 0; v < 8; v++) {
                float kv = krT[(u * 8 + v) * 64 + o];
#pragma unroll
                for (int x = 0; x < 8; x++)
                    outr[x] += kv * row[(x - v + 8) & 7];
            }
        }
        int gy = gy0 + y;
#pragma unroll
        for (int x = 0; x < 8; x++)
            e1[(gy * WW + gx0 + x) * 64 + o] = outr[x];
    }
}

// ---------------------------------------------------------------------------
// k_conv3: e3 = conv3x3(e1 + rev, w_conv2, pad 1).  Block = 16x4 tile + halo.
// ---------------------------------------------------------------------------
__global__ __launch_bounds__(256) void k_conv3(
    const float* __restrict__ e1, const float* __restrict__ rev,
    const float* __restrict__ w2T, float* __restrict__ e3)
{
    __shared__ __align__(16) float tl[108 * ROWP];   // halo tile 18x6 [hp][c]
    int t = threadIdx.x;
    int bx = blockIdx.x % 12, by = blockIdx.x / 12;
    int gx0 = bx * 16, gy0 = by * 4;

#pragma unroll
    for (int r = 0; r < 27; r++) {
        int idx = t + r * 256;          // 6912 = 108*64
        int c = idx & 63, hp = idx >> 6;
        int hy = hp / 18, hx = hp % 18;
        int gy = gy0 + hy - 1, gx = gx0 + hx - 1;
        float v = 0.f;
        if (gy >= 0 && gy < HH && gx >= 0 && gx < WW) {
            int gp = gy * WW + gx;
            v = e1[gp * 64 + c] + rev[gp * 64 + c];
        }
        tl[hp * ROWP + c] = v;
    }
    __syncthreads();

    int ot = (t >> 4) * 4, pxl = t & 15;
    float acc[4][4];
#pragma unroll
    for (int i = 0; i < 4; i++)
#pragma unroll
        for (int j = 0; j < 4; j++) acc[i][j] = 0.f;

    for (int tap = 0; tap < 9; tap++) {
        int dy = tap / 3, dx = tap % 3;
        const float* wt = w2T + tap * 4096;
#pragma unroll
        for (int c4 = 0; c4 < 16; c4++) {
            float4 wv[4], sv[4];
#pragma unroll
            for (int i = 0; i < 4; i++)
                wv[i] = *(const float4*)&wt[(ot + i) * 64 + c4 * 4];
#pragma unroll
            for (int j = 0; j < 4; j++) {
                int hp = (j + dy) * 18 + (pxl + dx);
                sv[j] = *(const float4*)&tl[hp * ROWP + c4 * 4];
            }
#pragma unroll
            for (int i = 0; i < 4; i++)
#pragma unroll
                for (int j = 0; j < 4; j++)
                    acc[i][j] += wv[i].x * sv[j].x + wv[i].y * sv[j].y
                               + wv[i].z * sv[j].z + wv[i].w * sv[j].w;
        }
    }
#pragma unroll
    for (int j = 0; j < 4; j++) {
        int gp = (gy0 + j) * WW + gx0 + pxl;
        float4 rv = make_float4(acc[0][j], acc[1][j], acc[2][j], acc[3][j]);
        *(float4*)&e3[gp * 64 + ot] = rv;
    }
}

// ---------------------------------------------------------------------------
// k_out: feat = [e3 ; dec], g = w_proj_out @ feat (128->128),
// out[o] = g[o] * g[o+64].  Block = 16x4 tile.
// ---------------------------------------------------------------------------
#define ROWF 132  // 128 + 4 pad, multiple of 4

__global__ __launch_bounds__(256) void k_out(
    const float* __restrict__ e3, const float* __restrict__ dec,
    const float* __restrict__ wpo, float* __restrict__ out)
{
    __shared__ __align__(16) float f[64 * ROWF];
    int t = threadIdx.x;
    int bx = blockIdx.x % 12, by = blockIdx.x / 12;
    int gx0 = bx * 16, gy0 = by * 4;

#pragma unroll
    for (int r = 0; r < 16; r++) {          // e3 half: lanes c-consecutive
        int idx = t + r * 256;
        int c = idx & 63, px = idx >> 6;
        int gp = (gy0 + (px >> 4)) * WW + gx0 + (px & 15);
        f[px * ROWF + c] = e3[gp * 64 + c];
    }
#pragma unroll
    for (int r = 0; r < 16; r++) {          // dec half: lanes px-consecutive
        int idx = t + r * 256;
        int px = idx & 63, c = idx >> 6;
        int gp = (gy0 + (px >> 4)) * WW + gx0 + (px & 15);
        f[px * ROWF + 64 + c] = dec[c * HWSZ + gp];
    }
    __syncthreads();

    int ot = (t >> 4) * 4, pxl = t & 15;
    float a1[4][4], a2[4][4];
#pragma unroll
    for (int i = 0; i < 4; i++)
#pragma unroll
        for (int j = 0; j < 4; j++) { a1[i][j] = 0.f; a2[i][j] = 0.f; }

#pragma unroll
    for (int c4 = 0; c4 < 32; c4++) {
        float4 w1[4], w2[4], sv[4];
#pragma unroll
        for (int i = 0; i < 4; i++) {
            w1[i] = *(const float4*)&wpo[(ot + i) * 128 + c4 * 4];
            w2[i] = *(const float4*)&wpo[(ot + i + 64) * 128 + c4 * 4];
        }
#pragma unroll
        for (int j = 0; j < 4; j++)
            sv[j] = *(const float4*)&f[(pxl + 16 * j) * ROWF + c4 * 4];
#pragma unroll
        for (int i = 0; i < 4; i++)
#pragma unroll
            for (int j = 0; j < 4; j++) {
                a1[i][j] += w1[i].x * sv[j].x + w1[i].y * sv[j].y
                          + w1[i].z * sv[j].z + w1[i].w * sv[j].w;
                a2[i][j] += w2[i].x * sv[j].x + w2[i].y * sv[j].y
                          + w2[i].z * sv[j].z + w2[i].w * sv[j].w;
            }
    }
#pragma unroll
    for (int j = 0; j < 4; j++) {
        int gp = (gy0 + j) * WW + gx0 + pxl;
#pragma unroll
        for (int i = 0; i < 4; i++)
            out[(ot + i) * HWSZ + gp] = a1[i][j] * a2[i][j];
    }
}

// ---------------------------------------------------------------------------
extern "C" void kernel_launch(void* const* d_in, const int* in_sizes, int n_in,
                              void* d_out, int out_size, void* d_ws, size_t ws_size,
                              hipStream_t stream)
{
    const float* enc  = (const float*)d_in[0];
    const float* dec  = (const float*)d_in[1];
    const float* ioff = (const float*)d_in[2];
    const float* iwt  = (const float*)d_in[3];
    const float* wpi  = (const float*)d_in[4];
    const float* fw   = (const float*)d_in[5];
    const float* wpo  = (const float*)d_in[6];
    const float* wd   = (const float*)d_in[7];
    const float* wc1  = (const float*)d_in[8];
    const float* wc2  = (const float*)d_in[9];
    float* out = (float*)d_out;
    float* ws  = (float*)d_ws;

    float* krT  = ws;                 //   4096
    float* wT   = ws + 4096;          // 200704
    float* w2T  = ws + 204800;        //  36864
    float* rev  = ws + 241664;        // 2359296  [px][64]
    float* e1   = ws + 2600960;       // 2359296  [px][64]
    float* e3   = ws + 4960256;       // 2359296  [px][64]
    float* encP = ws + 7319552;       // 2359296  [px][64]
    // total: 9678848 floats = 38.7 MB

    hipLaunchKernelGGL(k_prep,   dim3(256), dim3(256), 0, stream, fw, wd, wc2, krT, wT, w2T);
    hipLaunchKernelGGL(k_trans,  dim3(576), dim3(256), 0, stream, enc, encP);
    hipLaunchKernelGGL(k_deform, dim3(576), dim3(256), 0, stream, encP, ioff, iwt, wT, wc1, rev);
    hipLaunchKernelGGL(k_fft,    dim3(576), dim3(256), 0, stream, enc, wpi, krT, e1);
    hipLaunchKernelGGL(k_conv3,  dim3(576), dim3(256), 0, stream, e1, rev, w2T, e3);
    hipLaunchKernelGGL(k_out,    dim3(576), dim3(256), 0, stream, e3, dec, wpo, out);
}